// Round 1
// baseline (209.310 us; speedup 1.0000x reference)
//
#include <hip/hip_runtime.h>
#include <math.h>

#define NN   5000
#define INF_ 64
#define HID  32
#define NH   4
#define OUTF 64
#define NEG  0.2f
#define CAP  256   // max neighbors/row; E[deg]=100, sigma~10 -> 256 is >15 sigma safe

// ---------------- Kernel 1: Wh1 = h @ W1, s1_src/s1_dst scores ----------------
// grid NN x 128 threads; thread t -> output feature t (head t>>5, f t&31)
__global__ __launch_bounds__(128) void k_wh1(const float* __restrict__ h,
        const float* __restrict__ W1, const float* __restrict__ a1s,
        const float* __restrict__ a1d, float* __restrict__ Wh1,
        float* __restrict__ s1s, float* __restrict__ s1d) {
    const int n = blockIdx.x, t = threadIdx.x;
    __shared__ float hs[INF_];
    if (t < INF_) hs[t] = h[n * INF_ + t];
    __syncthreads();
    float acc = 0.f;
#pragma unroll
    for (int k = 0; k < INF_; ++k) acc += hs[k] * W1[k * (NH * HID) + t];
    Wh1[n * (NH * HID) + t] = acc;
    const int hd = t >> 5, f = t & 31;
    float vs = acc * a1s[hd * HID + f];
    float vd = acc * a1d[hd * HID + f];
    // reduce within 32-lane segments (one head per segment)
    for (int off = 16; off > 0; off >>= 1) {
        vs += __shfl_down(vs, off, 32);
        vd += __shfl_down(vd, off, 32);
    }
    if (f == 0) { s1s[n * NH + hd] = vs; s1d[n * NH + hd] = vd; }
}

// ---------------- Kernel 2: dense adj row -> compacted neighbor list ----------
__global__ __launch_bounds__(256) void k_csr(const float* __restrict__ adj,
        int* __restrict__ counts, int* __restrict__ idx) {
    const int i = blockIdx.x;
    __shared__ int cnt;
    if (threadIdx.x == 0) cnt = 0;
    __syncthreads();
    const float4* row4 = (const float4*)(adj + (size_t)i * NN);  // 20000B rows, 16B aligned
    int* my = idx + (size_t)i * CAP;
    for (int j = threadIdx.x; j < NN / 4; j += 256) {
        float4 v = row4[j];
        if (v.x > 0.f) { int p = atomicAdd(&cnt, 1); if (p < CAP) my[p] = 4 * j + 0; }
        if (v.y > 0.f) { int p = atomicAdd(&cnt, 1); if (p < CAP) my[p] = 4 * j + 1; }
        if (v.z > 0.f) { int p = atomicAdd(&cnt, 1); if (p < CAP) my[p] = 4 * j + 2; }
        if (v.w > 0.f) { int p = atomicAdd(&cnt, 1); if (p < CAP) my[p] = 4 * j + 3; }
    }
    __syncthreads();
    if (threadIdx.x == 0) counts[i] = cnt < CAP ? cnt : CAP;
}

// ---------------- Kernel 3: layer-1 attention + aggregate + ELU ---------------
// grid NN x 128 threads (2 waves). Block handles node i.
__global__ __launch_bounds__(128) void k_attn1(const int* __restrict__ counts,
        const int* __restrict__ idx, const float* __restrict__ Wh1,
        const float* __restrict__ s1s, const float* __restrict__ s1d,
        float* __restrict__ x) {
    const int i = blockIdx.x, t = threadIdx.x;
    const int c = counts[i];
    __shared__ int   nb[CAP];
    __shared__ float sc[CAP * NH];
    __shared__ float red[NH * 128];
    for (int e = t; e < c; e += 128) nb[e] = idx[(size_t)i * CAP + e];
    __syncthreads();
    float ssrc[NH];
#pragma unroll
    for (int hh = 0; hh < NH; ++hh) ssrc[hh] = s1s[i * NH + hh];
    // per-edge leaky-relu scores
    for (int e = t; e < c; e += 128) {
        const int j = nb[e];
#pragma unroll
        for (int hh = 0; hh < NH; ++hh) {
            float v = ssrc[hh] + s1d[j * NH + hh];
            v = (v >= 0.f) ? v : NEG * v;
            sc[e * NH + hh] = v;
        }
    }
    __syncthreads();
    // block max per head
    float lm[NH];
#pragma unroll
    for (int hh = 0; hh < NH; ++hh) lm[hh] = -1e30f;
    for (int e = t; e < c; e += 128)
#pragma unroll
        for (int hh = 0; hh < NH; ++hh) lm[hh] = fmaxf(lm[hh], sc[e * NH + hh]);
#pragma unroll
    for (int hh = 0; hh < NH; ++hh) red[hh * 128 + t] = lm[hh];
    __syncthreads();
    for (int s = 64; s > 0; s >>= 1) {
        if (t < s)
#pragma unroll
            for (int hh = 0; hh < NH; ++hh)
                red[hh * 128 + t] = fmaxf(red[hh * 128 + t], red[hh * 128 + t + s]);
        __syncthreads();
    }
    float m[NH];
#pragma unroll
    for (int hh = 0; hh < NH; ++hh) m[hh] = red[hh * 128];
    __syncthreads();
    // exp + block sum per head
    float ls[NH];
#pragma unroll
    for (int hh = 0; hh < NH; ++hh) ls[hh] = 0.f;
    for (int e = t; e < c; e += 128)
#pragma unroll
        for (int hh = 0; hh < NH; ++hh) {
            float v = expf(sc[e * NH + hh] - m[hh]);
            sc[e * NH + hh] = v;
            ls[hh] += v;
        }
    __syncthreads();
#pragma unroll
    for (int hh = 0; hh < NH; ++hh) red[hh * 128 + t] = ls[hh];
    __syncthreads();
    for (int s = 64; s > 0; s >>= 1) {
        if (t < s)
#pragma unroll
            for (int hh = 0; hh < NH; ++hh)
                red[hh * 128 + t] += red[hh * 128 + t + s];
        __syncthreads();
    }
    float l[NH];
#pragma unroll
    for (int hh = 0; hh < NH; ++hh) l[hh] = red[hh * 128];
    // aggregate: thread t -> (head t>>5, feature t&31); Wh1 rows are L2-resident
    const int hd = t >> 5;
    float acc = 0.f;
    for (int e = 0; e < c; ++e)
        acc += sc[e * NH + hd] * Wh1[(size_t)nb[e] * (NH * HID) + t];
    float o = acc / l[hd];
    o = (o > 0.f) ? o : expm1f(o);   // ELU (alpha=1)
    x[i * (NH * HID) + t] = o;
}

// ---------------- Kernel 4: Wh2 = x @ W2, s2 scores (1 wave/node) -------------
__global__ __launch_bounds__(64) void k_wh2(const float* __restrict__ x,
        const float* __restrict__ W2, const float* __restrict__ a2s,
        const float* __restrict__ a2d, float* __restrict__ Wh2,
        float* __restrict__ s2s, float* __restrict__ s2d) {
    const int n = blockIdx.x, t = threadIdx.x;
    __shared__ float xs[NH * HID];
    xs[t] = x[n * 128 + t];
    xs[t + 64] = x[n * 128 + 64 + t];
    __syncthreads();
    float acc = 0.f;
#pragma unroll
    for (int k = 0; k < 128; ++k) acc += xs[k] * W2[k * OUTF + t];
    Wh2[n * OUTF + t] = acc;
    float vs = acc * a2s[t];
    float vd = acc * a2d[t];
    for (int off = 32; off > 0; off >>= 1) {
        vs += __shfl_down(vs, off, 64);
        vd += __shfl_down(vd, off, 64);
    }
    if (t == 0) { s2s[n] = vs; s2d[n] = vd; }
}

// ---------------- Kernel 5: layer-2 attention -> d_out ------------------------
__global__ __launch_bounds__(64) void k_attn2(const int* __restrict__ counts,
        const int* __restrict__ idx, const float* __restrict__ Wh2,
        const float* __restrict__ s2s, const float* __restrict__ s2d,
        float* __restrict__ out) {
    const int i = blockIdx.x, t = threadIdx.x;
    const int c = counts[i];
    __shared__ int   nb[CAP];
    __shared__ float sc[CAP];
    for (int e = t; e < c; e += 64) nb[e] = idx[(size_t)i * CAP + e];
    __syncthreads();
    const float si = s2s[i];
    float lm = -1e30f;
    for (int e = t; e < c; e += 64) {
        float v = si + s2d[nb[e]];
        v = (v >= 0.f) ? v : NEG * v;
        sc[e] = v;
        lm = fmaxf(lm, v);
    }
    for (int off = 32; off > 0; off >>= 1) lm = fmaxf(lm, __shfl_down(lm, off, 64));
    lm = __shfl(lm, 0, 64);
    float ls = 0.f;
    for (int e = t; e < c; e += 64) {
        float v = expf(sc[e] - lm);
        sc[e] = v;
        ls += v;
    }
    __syncthreads();
    for (int off = 32; off > 0; off >>= 1) ls += __shfl_down(ls, off, 64);
    ls = __shfl(ls, 0, 64);
    float acc = 0.f;
    for (int e = 0; e < c; ++e)
        acc += sc[e] * Wh2[(size_t)nb[e] * OUTF + t];
    out[i * OUTF + t] = acc / ls;
}

extern "C" void kernel_launch(void* const* d_in, const int* in_sizes, int n_in,
                              void* d_out, int out_size, void* d_ws, size_t ws_size,
                              hipStream_t stream) {
    const float* adj = (const float*)d_in[0];
    const float* h   = (const float*)d_in[1];
    const float* W1  = (const float*)d_in[2];
    const float* a1s = (const float*)d_in[3];
    const float* a1d = (const float*)d_in[4];
    const float* W2  = (const float*)d_in[5];
    const float* a2s = (const float*)d_in[6];
    const float* a2d = (const float*)d_in[7];
    float* out = (float*)d_out;

    // workspace layout (all 16B aligned; total ~11.2 MB)
    char* p = (char*)d_ws;
    float* Wh1 = (float*)p; p += (size_t)NN * 128 * 4;
    float* xbuf= (float*)p; p += (size_t)NN * 128 * 4;
    float* Wh2 = (float*)p; p += (size_t)NN * OUTF * 4;
    float* s1s = (float*)p; p += (size_t)NN * NH * 4;
    float* s1d = (float*)p; p += (size_t)NN * NH * 4;
    float* s2s = (float*)p; p += (size_t)NN * 4;
    float* s2d = (float*)p; p += (size_t)NN * 4;
    int*   cnt = (int*)p;   p += (size_t)NN * 4;
    int*   idx = (int*)p;   p += (size_t)NN * CAP * 4;

    k_csr  <<<NN, 256, 0, stream>>>(adj, cnt, idx);
    k_wh1  <<<NN, 128, 0, stream>>>(h, W1, a1s, a1d, Wh1, s1s, s1d);
    k_attn1<<<NN, 128, 0, stream>>>(cnt, idx, Wh1, s1s, s1d, xbuf);
    k_wh2  <<<NN,  64, 0, stream>>>(xbuf, W2, a2s, a2d, Wh2, s2s, s2d);
    k_attn2<<<NN,  64, 0, stream>>>(cnt, idx, Wh2, s2s, s2d, out);
}